// Round 10
// baseline (195.018 us; speedup 1.0000x reference)
//
#include <hip/hip_runtime.h>
#include <math.h>

#define LQ 2048
#define NH 8
#define DD 64
#define SK 80
#define UTOP 80
#define NB 2
#define CH 32        // number of key chunks per (b,h)
#define CK2 64       // keys per chunk (processed as 2 sub-chunks of 32)
#define CKS 32       // keys per sub-chunk

// ---------------- Kernel A (fused with V_mean fill) ----------------------------
// Exact R8 geometry (measured best: kA ~37 us): wave = one (b,h,l), 16 lanes
// per sample, 20 gathers in flight, DPP-based 16-lane reduce on the VALU pipe.
// V_mean blocks additionally zero the kD completion counters.
__global__ __launch_bounds__(256) void kA_M(const float* __restrict__ Q,
                                            const float* __restrict__ K,
                                            const float* __restrict__ V,
                                            const int* __restrict__ idxs,
                                            float* __restrict__ M,
                                            float* __restrict__ out,
                                            int* __restrict__ cnt) {
    __shared__ float4 red[16][16];
    int tid = threadIdx.x;
    int x = blockIdx.x;
    if (x < 16) {
        if (tid == 0) cnt[x] = 0;        // zero kD's completion counters
        // ---- V_mean fill: one block per (b,h) ----
        int b = x >> 3, h = x & 7;
        int d4 = tid & 15, ls = tid >> 4;
        const float4* V4 = (const float4*)V;
        float4 s = make_float4(0.f, 0.f, 0.f, 0.f);
        for (int i = 0; i < 128; ++i) {
            int l = (i << 4) + ls;
            float4 v = V4[(((size_t)(b * LQ + l) * NH + h) << 4) + d4];
            s.x += v.x; s.y += v.y; s.z += v.z; s.w += v.w;
        }
        red[ls][d4] = s;
        __syncthreads();
        if (ls == 0) {
            float4 t = red[0][d4];
            for (int k = 1; k < 16; ++k) {
                float4 r = red[k][d4];
                t.x += r.x; t.y += r.y; t.z += r.z; t.w += r.w;
            }
            t.x *= (1.f / 2048.f); t.y *= (1.f / 2048.f);
            t.z *= (1.f / 2048.f); t.w *= (1.f / 2048.f);
            red[0][d4] = t;
        }
        __syncthreads();
        float4* out4 = (float4*)out;
        for (int f = tid; f < UTOP * 16; f += 256) {
            int r = f >> 4, dd = f & 15;
            out4[(((size_t)(b * UTOP + r) * NH + h) << 4) + dd] = red[0][dd];
        }
        return;
    }
    x -= 16;                            // 16 % 8 == 0: XCD parity preserved
    int h = x & 7;                      // XCD-pinned head
    int b = (x >> 3) & 1;
    int l = ((x >> 4) << 2) + (tid >> 6);   // one l per wave
    int lane = tid & 63;
    int g = lane >> 4;                  // 16-lane row == sample group 0..3
    int t = lane & 15;                  // float4 slot within the 64-float row
    const float4* Q4 = (const float4*)Q;
    const float4* K4 = (const float4*)K;
    float4 q4 = Q4[(((size_t)(b * LQ + l) * NH + h) << 4) + t];
    const int* idxrow = idxs + l * SK;
    int kidx[20];
#pragma unroll
    for (int it = 0; it < 20; ++it) kidx[it] = idxrow[(it << 2) + g];
    __builtin_amdgcn_sched_barrier(0);   // all 20 index loads issued first
    float4 kb[20];
#pragma unroll
    for (int it = 0; it < 20; ++it)
        kb[it] = K4[(((size_t)(b * LQ + kidx[it]) * NH + h) << 4) + t];
    __builtin_amdgcn_sched_barrier(0);   // all 20 gathers in flight before use
    float maxv = -INFINITY, sumv = 0.f;
#pragma unroll
    for (int it = 0; it < 20; ++it) {
        float4 k4 = kb[it];
        float p = q4.x * k4.x + q4.y * k4.y + q4.z * k4.z + q4.w * k4.w;
        // 16-lane allreduce on the VALU pipe (row-local DPP):
        p += __int_as_float(__builtin_amdgcn_update_dpp(
                 0, __float_as_int(p), 177, 0xf, 0xf, false));   // quad xor1
        p += __int_as_float(__builtin_amdgcn_update_dpp(
                 0, __float_as_int(p), 78, 0xf, 0xf, false));    // quad xor2
        p += __int_as_float(__builtin_amdgcn_update_dpp(
                 0, __float_as_int(p), 0x141, 0xf, 0xf, false)); // half mirror
        p += __int_as_float(__builtin_amdgcn_update_dpp(
                 0, __float_as_int(p), 0x140, 0xf, 0xf, false)); // row mirror
        maxv = fmaxf(maxv, p);
        sumv += p;
    }
    maxv = fmaxf(maxv, __shfl_xor(maxv, 16));
    maxv = fmaxf(maxv, __shfl_xor(maxv, 32));
    sumv += __shfl_xor(sumv, 16);
    sumv += __shfl_xor(sumv, 32);
    if (lane == 0) M[(b * NH + h) * LQ + l] = maxv - sumv * (1.f / 2048.f);
}

// ---------------- Kernel B: exact top-80 SET via 48-bit radix select ------------
__global__ __launch_bounds__(256) void kB_topk(const float* __restrict__ M,
                                               int* __restrict__ Mtop,
                                               int* __restrict__ Winfo) {
    int bh = blockIdx.x;  // 0..15 == b*8+h
    int tid = threadIdx.x;
    int lane = tid & 63, w = tid >> 6;
    __shared__ unsigned long long keys[LQ];   // 16 KB
    __shared__ int hist[256];
    __shared__ int wavered[4];
    __shared__ int s_need;
    __shared__ unsigned long long s_prefix;
    __shared__ int s_cnt;
    __shared__ unsigned long long s_win;
    const float* Mrow = M + bh * LQ;
#pragma unroll
    for (int i = 0; i < 8; ++i) {
        int e = i * 256 + tid;                       // coalesced
        unsigned int bits = __float_as_uint(Mrow[e]);
        bits ^= (unsigned int)(((int)bits >> 31)) | 0x80000000u;   // monotone
        keys[e] = ((unsigned long long)bits << 16) | (unsigned int)(2047 - e);
    }
    if (tid == 0) { s_need = UTOP; s_prefix = 0ull; s_cnt = 0; s_win = ~0ull; }
    __syncthreads();
#pragma unroll
    for (int pass = 0; pass < 6; ++pass) {
        int shift = 40 - pass * 8;
        int need = s_need;
        unsigned long long pref = s_prefix;
        hist[tid] = 0;
        __syncthreads();
        unsigned long long prefmask = ~((1ull << (shift + 8)) - 1ull);
#pragma unroll
        for (int i = 0; i < 8; ++i) {
            unsigned long long k = keys[i * 256 + tid];
            if ((k & prefmask) == pref)
                atomicAdd(&hist[(int)((k >> shift) & 255)], 1);
        }
        __syncthreads();
        int b = 255 - tid;                 // suffix count via prefix scan on tid
        int v = hist[b];
        int x = v;
#pragma unroll
        for (int off = 1; off < 64; off <<= 1) {
            int y = __shfl_up(x, off);
            if (lane >= off) x += y;
        }
        if (lane == 63) wavered[w] = x;
        __syncthreads();
        int add = 0;
        for (int ww = 0; ww < w; ++ww) add += wavered[ww];
        int C = x + add;                   // = count of keys in bins >= b
        if (C >= need && C - v < need) {   // crossing bin (exactly one thread)
            s_need = need - (C - v);
            s_prefix = pref | ((unsigned long long)b << shift);
        }
        __syncthreads();
    }
    unsigned long long kth = s_prefix;     // exact 80th-largest key
#pragma unroll
    for (int i = 0; i < 8; ++i) {
        unsigned long long k = keys[i * 256 + tid];
        if (k >= kth) {
            int slot = atomicAdd(&s_cnt, 1);
            int q = 2047 - (int)(k & 0xffffu);
            Mtop[bh * UTOP + slot] = q;
            if (q >= UTOP - 1) atomicMin(&s_win, k);   // last-in-rank among idx>=79
        }
    }
    __syncthreads();
    if (tid == 0) Winfo[bh] = 2047 - (int)(s_win & 0xffffu);
}

// ---------------- Kernel D: flash partials + fused last-block combine -----------
// Compute body identical to R8. Epilogue: device-scope completion counter per
// bhl; the 32nd-arriving block re-reads all chunks' partials and writes the
// output rows (former kE), with alpha scalars staged in the now-dead Qs LDS.
__global__ __launch_bounds__(256) void kD_attn(const float* __restrict__ Q,
                                               const float* __restrict__ K,
                                               const float* __restrict__ V,
                                               const int* __restrict__ Mtop,
                                               const int* __restrict__ Winfo,
                                               float* __restrict__ part_m,
                                               float* __restrict__ part_l,
                                               float* __restrict__ part_acc,
                                               int* __restrict__ cnt,
                                               float* __restrict__ out) {
    int code = blockIdx.x & 15;
    int b = code & 1, h = code >> 1;
    int bhl = b * NH + h;
    int c = blockIdx.x >> 4;                  // 0..31
    __shared__ int topl[UTOP];
    __shared__ __align__(16) float Qs[UTOP][68];
    __shared__ __align__(16) float Ks[CKS][68];
    __shared__ __align__(16) float Vs[CKS][68];
    __shared__ __align__(16) float Ps[UTOP][36];   // 16B-aligned rows for b128
    __shared__ int s_last;
    int tid = threadIdx.x;
    if (tid < UTOP) topl[tid] = Mtop[bhl * UTOP + tid];
    __syncthreads();
    for (int f = tid; f < UTOP * 16; f += 256) {
        int u = f >> 4, t4 = f & 15;
        const float4* src = (const float4*)(Q + (((size_t)(b * LQ + topl[u]) * NH + h) << 6));
        *((float4*)&Qs[u][t4 << 2]) = src[t4];
    }
    int i = tid >> 4, j = tid & 15;
    const float scale = 0.125f;
    float4 acc[5];
    float m_run[5], l_run[5];
#pragma unroll
    for (int n = 0; n < 5; ++n) {
        acc[n] = make_float4(0.f, 0.f, 0.f, 0.f);
        m_run[n] = -INFINITY;
        l_run[n] = 0.f;
    }
    for (int sc = 0; sc < 2; ++sc) {
        __syncthreads();
        int kbase = c * CK2 + sc * CKS;
        for (int f = tid; f < CKS * 16; f += 256) {
            int k = f >> 4, t4 = f & 15;
            const float4* srck = (const float4*)(K + (((size_t)(b * LQ + kbase + k) * NH + h) << 6));
            *((float4*)&Ks[k][t4 << 2]) = srck[t4];
            const float4* srcv = (const float4*)(V + (((size_t)(b * LQ + kbase + k) * NH + h) << 6));
            *((float4*)&Vs[k][t4 << 2]) = srcv[t4];
        }
        __syncthreads();
        float s0[5], s1[5];
#pragma unroll
        for (int n = 0; n < 5; ++n) { s0[n] = 0.f; s1[n] = 0.f; }
#pragma unroll
        for (int d4 = 0; d4 < 16; ++d4) {
            float4 ka = *((float4*)&Ks[j][d4 << 2]);
            float4 kb = *((float4*)&Ks[j + 16][d4 << 2]);
#pragma unroll
            for (int n = 0; n < 5; ++n) {
                float4 q4 = *((float4*)&Qs[i * 5 + n][d4 << 2]);
                s0[n] += q4.x * ka.x + q4.y * ka.y + q4.z * ka.z + q4.w * ka.w;
                s1[n] += q4.x * kb.x + q4.y * kb.y + q4.z * kb.z + q4.w * kb.w;
            }
        }
        float m32[5], l32[5];
#pragma unroll
        for (int n = 0; n < 5; ++n) {
            float a = s0[n] * scale, bb = s1[n] * scale;
            float m = fmaxf(a, bb);
#pragma unroll
            for (int off = 1; off < 16; off <<= 1) m = fmaxf(m, __shfl_xor(m, off, 16));
            float p0 = __expf(a - m), p1 = __expf(bb - m);
            float ls = p0 + p1;
#pragma unroll
            for (int off = 1; off < 16; off <<= 1) ls += __shfl_xor(ls, off, 16);
            int u = i * 5 + n;
            Ps[u][j] = p0;
            Ps[u][j + 16] = p1;
            m32[n] = m;
            l32[n] = ls;
        }
        __syncthreads();
        // PV: k-tiles of 8, Vs rows read once, P rows via b128 broadcast
        float4 pv[5];
#pragma unroll
        for (int n = 0; n < 5; ++n) pv[n] = make_float4(0.f, 0.f, 0.f, 0.f);
#pragma unroll
        for (int kt = 0; kt < 4; ++kt) {
            float4 pA[5], pB[5];
#pragma unroll
            for (int n = 0; n < 5; ++n) {
                pA[n] = *((float4*)&Ps[i * 5 + n][kt * 8]);
                pB[n] = *((float4*)&Ps[i * 5 + n][kt * 8 + 4]);
            }
#pragma unroll
            for (int kk = 0; kk < 8; ++kk) {
                float4 v4 = *((float4*)&Vs[kt * 8 + kk][j << 2]);
#pragma unroll
                for (int n = 0; n < 5; ++n) {
                    float p = (kk < 4) ? ((float*)&pA[n])[kk] : ((float*)&pB[n])[kk - 4];
                    pv[n].x += p * v4.x; pv[n].y += p * v4.y;
                    pv[n].z += p * v4.z; pv[n].w += p * v4.w;
                }
            }
        }
#pragma unroll
        for (int n = 0; n < 5; ++n) {
            float m_new = fmaxf(m_run[n], m32[n]);
            float fo = __expf(m_run[n] - m_new);
            float fn = __expf(m32[n] - m_new);
            l_run[n] = l_run[n] * fo + l32[n] * fn;
            acc[n].x = acc[n].x * fo + fn * pv[n].x;
            acc[n].y = acc[n].y * fo + fn * pv[n].y;
            acc[n].z = acc[n].z * fo + fn * pv[n].z;
            acc[n].w = acc[n].w * fo + fn * pv[n].w;
            m_run[n] = m_new;
        }
    }
#pragma unroll
    for (int n = 0; n < 5; ++n) {
        int u = i * 5 + n;
        size_t base = ((size_t)(bhl * CH + c) * UTOP + u);
        if (j == 0) {
            part_m[base] = m_run[n];
            part_l[base] = l_run[n];
        }
        *((float4*)&part_acc[base * DD + (j << 2)]) = acc[n];
    }
    // ---- fused combine: last-arriving block per bhl does the former kE ----
    __threadfence();                      // release this block's partials
    __syncthreads();
    if (tid == 0) {
        int old = atomicAdd(&cnt[bhl], 1);   // device-scope [m20]
        s_last = (old == CH - 1) ? 1 : 0;
    }
    __syncthreads();
    if (!s_last) return;
    __threadfence();                      // acquire: invalidate stale L2 lines
    // phase 1: per-u scalars; alpha staged in Qs[u][c], lsum in Ps[u][0]
    if (tid < UTOP) {
        int u = tid;
        float mu = -INFINITY;
        for (int c2 = 0; c2 < CH; ++c2)
            mu = fmaxf(mu, part_m[((size_t)(bhl * CH + c2)) * UTOP + u]);
        float ls = 0.f;
        for (int c2 = 0; c2 < CH; ++c2) {
            float a = __expf(part_m[((size_t)(bhl * CH + c2)) * UTOP + u] - mu);
            ls += part_l[((size_t)(bhl * CH + c2)) * UTOP + u] * a;
            Qs[u][c2] = a;
        }
        Ps[u][0] = ls;
    }
    __syncthreads();
    int wq = Winfo[bhl];
    for (int w2 = tid; w2 < UTOP * DD; w2 += 256) {
        int u = w2 >> 6, d = w2 & 63;
        int qq = topl[u];
        int r;
        if (qq < UTOP - 1) r = qq;
        else { if (qq != wq) continue; r = UTOP - 1; }
        float acc2 = 0.f;
#pragma unroll 8
        for (int c2 = 0; c2 < CH; ++c2)
            acc2 += Qs[u][c2] *
                    part_acc[(((size_t)(bhl * CH + c2)) * UTOP + u) * DD + d];
        out[(((size_t)(b * UTOP + r)) * NH + h) * DD + d] = acc2 / Ps[u][0];
    }
}

extern "C" void kernel_launch(void* const* d_in, const int* in_sizes, int n_in,
                              void* d_out, int out_size, void* d_ws, size_t ws_size,
                              hipStream_t stream) {
    const float* Q = (const float*)d_in[0];
    const float* K = (const float*)d_in[1];
    const float* V = (const float*)d_in[2];
    const int* idxs = (const int*)d_in[3];
    float* out = (float*)d_out;

    char* base = (char*)d_ws;
    float* M        = (float*)(base + 0);          // 131072 B
    int*   Mtop     = (int*)  (base + 131072);     // 5120 B
    int*   Winfo    = (int*)  (base + 136192);     // 64 B
    float* part_m   = (float*)(base + 136256);     // 163840 B
    float* part_l   = (float*)(base + 300096);     // 163840 B
    float* part_acc = (float*)(base + 463936);     // 10485760 B
    int*   cnt      = (int*)  (base + 10949696);   // 64 B

    kA_M   <<<8192 + 16, 256, 0, stream>>>(Q, K, V, idxs, M, out, cnt);
    kB_topk<<<16,   256, 0, stream>>>(M, Mtop, Winfo);
    kD_attn<<<16 * CH, 256, 0, stream>>>(Q, K, V, Mtop, Winfo,
                                         part_m, part_l, part_acc, cnt, out);
}

// Round 11
// 133.946 us; speedup vs baseline: 1.4559x; 1.4559x over previous
//
#include <hip/hip_runtime.h>
#include <math.h>

#define LQ 2048
#define NH 8
#define DD 64
#define SK 80
#define UTOP 80
#define NB 2
#define CH 32        // number of key chunks per (b,h)
#define CK2 64       // keys per chunk (processed as 2 sub-chunks of 32)
#define CKS 32       // keys per sub-chunk

// ---------------- Kernel A (fused with V_mean fill) ----------------------------
// R8 geometry — measured best. Wave = one (b,h,l); 16 lanes per sample read a
// full 256B K row (2 whole cache lines, zero waste); 20 gathers in flight;
// 16-lane allreduce via 4 VALU-pipe DPP ops (no LDS-pipe ds_swizzle).
// NOTE (R9/R10 post-mortems): wave-uniform全-head variant regressed (+7) due to
// index-load VGPR pressure; last-block kE fusion regressed (+62) due to
// device-scope fence storms. Do not revisit without new counter evidence.
__global__ __launch_bounds__(256) void kA_M(const float* __restrict__ Q,
                                            const float* __restrict__ K,
                                            const float* __restrict__ V,
                                            const int* __restrict__ idxs,
                                            float* __restrict__ M,
                                            float* __restrict__ out) {
    __shared__ float4 red[16][16];
    int tid = threadIdx.x;
    int x = blockIdx.x;
    if (x < 16) {
        // ---- V_mean fill: one block per (b,h) ----
        int b = x >> 3, h = x & 7;
        int d4 = tid & 15, ls = tid >> 4;
        const float4* V4 = (const float4*)V;
        float4 s = make_float4(0.f, 0.f, 0.f, 0.f);
        for (int i = 0; i < 128; ++i) {
            int l = (i << 4) + ls;
            float4 v = V4[(((size_t)(b * LQ + l) * NH + h) << 4) + d4];
            s.x += v.x; s.y += v.y; s.z += v.z; s.w += v.w;
        }
        red[ls][d4] = s;
        __syncthreads();
        if (ls == 0) {
            float4 t = red[0][d4];
            for (int k = 1; k < 16; ++k) {
                float4 r = red[k][d4];
                t.x += r.x; t.y += r.y; t.z += r.z; t.w += r.w;
            }
            t.x *= (1.f / 2048.f); t.y *= (1.f / 2048.f);
            t.z *= (1.f / 2048.f); t.w *= (1.f / 2048.f);
            red[0][d4] = t;
        }
        __syncthreads();
        float4* out4 = (float4*)out;
        for (int f = tid; f < UTOP * 16; f += 256) {
            int r = f >> 4, dd = f & 15;
            out4[(((size_t)(b * UTOP + r) * NH + h) << 4) + dd] = red[0][dd];
        }
        return;
    }
    x -= 16;                            // 16 % 8 == 0: XCD parity preserved
    int h = x & 7;                      // XCD-pinned head
    int b = (x >> 3) & 1;
    int l = ((x >> 4) << 2) + (tid >> 6);   // one l per wave
    int lane = tid & 63;
    int g = lane >> 4;                  // 16-lane row == sample group 0..3
    int t = lane & 15;                  // float4 slot within the 64-float row
    const float4* Q4 = (const float4*)Q;
    const float4* K4 = (const float4*)K;
    float4 q4 = Q4[(((size_t)(b * LQ + l) * NH + h) << 4) + t];
    const int* idxrow = idxs + l * SK;
    int kidx[20];
#pragma unroll
    for (int it = 0; it < 20; ++it) kidx[it] = idxrow[(it << 2) + g];
    __builtin_amdgcn_sched_barrier(0);   // all 20 index loads issued first
    float4 kb[20];
#pragma unroll
    for (int it = 0; it < 20; ++it)
        kb[it] = K4[(((size_t)(b * LQ + kidx[it]) * NH + h) << 4) + t];
    __builtin_amdgcn_sched_barrier(0);   // all 20 gathers in flight before use
    float maxv = -INFINITY, sumv = 0.f;
#pragma unroll
    for (int it = 0; it < 20; ++it) {
        float4 k4 = kb[it];
        float p = q4.x * k4.x + q4.y * k4.y + q4.z * k4.z + q4.w * k4.w;
        // 16-lane allreduce on the VALU pipe (row-local DPP):
        p += __int_as_float(__builtin_amdgcn_update_dpp(
                 0, __float_as_int(p), 177, 0xf, 0xf, false));   // quad xor1
        p += __int_as_float(__builtin_amdgcn_update_dpp(
                 0, __float_as_int(p), 78, 0xf, 0xf, false));    // quad xor2
        p += __int_as_float(__builtin_amdgcn_update_dpp(
                 0, __float_as_int(p), 0x141, 0xf, 0xf, false)); // half mirror
        p += __int_as_float(__builtin_amdgcn_update_dpp(
                 0, __float_as_int(p), 0x140, 0xf, 0xf, false)); // row mirror
        maxv = fmaxf(maxv, p);
        sumv += p;
    }
    maxv = fmaxf(maxv, __shfl_xor(maxv, 16));
    maxv = fmaxf(maxv, __shfl_xor(maxv, 32));
    sumv += __shfl_xor(sumv, 16);
    sumv += __shfl_xor(sumv, 32);
    if (lane == 0) M[(b * NH + h) * LQ + l] = maxv - sumv * (1.f / 2048.f);
}

// ---------------- Kernel B: exact top-80 SET via 48-bit radix select ------------
__global__ __launch_bounds__(256) void kB_topk(const float* __restrict__ M,
                                               int* __restrict__ Mtop,
                                               int* __restrict__ Winfo) {
    int bh = blockIdx.x;  // 0..15 == b*8+h
    int tid = threadIdx.x;
    int lane = tid & 63, w = tid >> 6;
    __shared__ unsigned long long keys[LQ];   // 16 KB
    __shared__ int hist[256];
    __shared__ int wavered[4];
    __shared__ int s_need;
    __shared__ unsigned long long s_prefix;
    __shared__ int s_cnt;
    __shared__ unsigned long long s_win;
    const float* Mrow = M + bh * LQ;
#pragma unroll
    for (int i = 0; i < 8; ++i) {
        int e = i * 256 + tid;                       // coalesced
        unsigned int bits = __float_as_uint(Mrow[e]);
        bits ^= (unsigned int)(((int)bits >> 31)) | 0x80000000u;   // monotone
        keys[e] = ((unsigned long long)bits << 16) | (unsigned int)(2047 - e);
    }
    if (tid == 0) { s_need = UTOP; s_prefix = 0ull; s_cnt = 0; s_win = ~0ull; }
    __syncthreads();
#pragma unroll
    for (int pass = 0; pass < 6; ++pass) {
        int shift = 40 - pass * 8;
        int need = s_need;
        unsigned long long pref = s_prefix;
        hist[tid] = 0;
        __syncthreads();
        unsigned long long prefmask = ~((1ull << (shift + 8)) - 1ull);
#pragma unroll
        for (int i = 0; i < 8; ++i) {
            unsigned long long k = keys[i * 256 + tid];
            if ((k & prefmask) == pref)
                atomicAdd(&hist[(int)((k >> shift) & 255)], 1);
        }
        __syncthreads();
        int b = 255 - tid;                 // suffix count via prefix scan on tid
        int v = hist[b];
        int x = v;
#pragma unroll
        for (int off = 1; off < 64; off <<= 1) {
            int y = __shfl_up(x, off);
            if (lane >= off) x += y;
        }
        if (lane == 63) wavered[w] = x;
        __syncthreads();
        int add = 0;
        for (int ww = 0; ww < w; ++ww) add += wavered[ww];
        int C = x + add;                   // = count of keys in bins >= b
        if (C >= need && C - v < need) {   // crossing bin (exactly one thread)
            s_need = need - (C - v);
            s_prefix = pref | ((unsigned long long)b << shift);
        }
        __syncthreads();
    }
    unsigned long long kth = s_prefix;     // exact 80th-largest key
#pragma unroll
    for (int i = 0; i < 8; ++i) {
        unsigned long long k = keys[i * 256 + tid];
        if (k >= kth) {
            int slot = atomicAdd(&s_cnt, 1);
            int q = 2047 - (int)(k & 0xffffu);
            Mtop[bh * UTOP + slot] = q;
            if (q >= UTOP - 1) atomicMin(&s_win, k);   // last-in-rank among idx>=79
        }
    }
    __syncthreads();
    if (tid == 0) Winfo[bh] = 2047 - (int)(s_win & 0xffffu);
}

// ---------------- Kernel D: flash partials over 64-key chunks (2x32 sub-chunks) -
__global__ __launch_bounds__(256) void kD_attn(const float* __restrict__ Q,
                                               const float* __restrict__ K,
                                               const float* __restrict__ V,
                                               const int* __restrict__ Mtop,
                                               float* __restrict__ part_m,
                                               float* __restrict__ part_l,
                                               float* __restrict__ part_acc) {
    int code = blockIdx.x & 15;
    int b = code & 1, h = code >> 1;
    int bhl = b * NH + h;
    int c = blockIdx.x >> 4;                  // 0..31
    __shared__ int topl[UTOP];
    __shared__ __align__(16) float Qs[UTOP][68];
    __shared__ __align__(16) float Ks[CKS][68];
    __shared__ __align__(16) float Vs[CKS][68];
    __shared__ __align__(16) float Ps[UTOP][36];   // 16B-aligned rows for b128
    int tid = threadIdx.x;
    if (tid < UTOP) topl[tid] = Mtop[bhl * UTOP + tid];
    __syncthreads();
    for (int f = tid; f < UTOP * 16; f += 256) {
        int u = f >> 4, t4 = f & 15;
        const float4* src = (const float4*)(Q + (((size_t)(b * LQ + topl[u]) * NH + h) << 6));
        *((float4*)&Qs[u][t4 << 2]) = src[t4];
    }
    int i = tid >> 4, j = tid & 15;
    const float scale = 0.125f;
    float4 acc[5];
    float m_run[5], l_run[5];
#pragma unroll
    for (int n = 0; n < 5; ++n) {
        acc[n] = make_float4(0.f, 0.f, 0.f, 0.f);
        m_run[n] = -INFINITY;
        l_run[n] = 0.f;
    }
    for (int sc = 0; sc < 2; ++sc) {
        __syncthreads();
        int kbase = c * CK2 + sc * CKS;
        for (int f = tid; f < CKS * 16; f += 256) {
            int k = f >> 4, t4 = f & 15;
            const float4* srck = (const float4*)(K + (((size_t)(b * LQ + kbase + k) * NH + h) << 6));
            *((float4*)&Ks[k][t4 << 2]) = srck[t4];
            const float4* srcv = (const float4*)(V + (((size_t)(b * LQ + kbase + k) * NH + h) << 6));
            *((float4*)&Vs[k][t4 << 2]) = srcv[t4];
        }
        __syncthreads();
        float s0[5], s1[5];
#pragma unroll
        for (int n = 0; n < 5; ++n) { s0[n] = 0.f; s1[n] = 0.f; }
#pragma unroll
        for (int d4 = 0; d4 < 16; ++d4) {
            float4 ka = *((float4*)&Ks[j][d4 << 2]);
            float4 kb = *((float4*)&Ks[j + 16][d4 << 2]);
#pragma unroll
            for (int n = 0; n < 5; ++n) {
                float4 q4 = *((float4*)&Qs[i * 5 + n][d4 << 2]);
                s0[n] += q4.x * ka.x + q4.y * ka.y + q4.z * ka.z + q4.w * ka.w;
                s1[n] += q4.x * kb.x + q4.y * kb.y + q4.z * kb.z + q4.w * kb.w;
            }
        }
        float m32[5], l32[5];
#pragma unroll
        for (int n = 0; n < 5; ++n) {
            float a = s0[n] * scale, bb = s1[n] * scale;
            float m = fmaxf(a, bb);
#pragma unroll
            for (int off = 1; off < 16; off <<= 1) m = fmaxf(m, __shfl_xor(m, off, 16));
            float p0 = __expf(a - m), p1 = __expf(bb - m);
            float ls = p0 + p1;
#pragma unroll
            for (int off = 1; off < 16; off <<= 1) ls += __shfl_xor(ls, off, 16);
            int u = i * 5 + n;
            Ps[u][j] = p0;
            Ps[u][j + 16] = p1;
            m32[n] = m;
            l32[n] = ls;
        }
        __syncthreads();
        // PV: k-tiles of 8, Vs rows read once, P rows via b128 broadcast
        float4 pv[5];
#pragma unroll
        for (int n = 0; n < 5; ++n) pv[n] = make_float4(0.f, 0.f, 0.f, 0.f);
#pragma unroll
        for (int kt = 0; kt < 4; ++kt) {
            float4 pA[5], pB[5];
#pragma unroll
            for (int n = 0; n < 5; ++n) {
                pA[n] = *((float4*)&Ps[i * 5 + n][kt * 8]);
                pB[n] = *((float4*)&Ps[i * 5 + n][kt * 8 + 4]);
            }
#pragma unroll
            for (int kk = 0; kk < 8; ++kk) {
                float4 v4 = *((float4*)&Vs[kt * 8 + kk][j << 2]);
#pragma unroll
                for (int n = 0; n < 5; ++n) {
                    float p = (kk < 4) ? ((float*)&pA[n])[kk] : ((float*)&pB[n])[kk - 4];
                    pv[n].x += p * v4.x; pv[n].y += p * v4.y;
                    pv[n].z += p * v4.z; pv[n].w += p * v4.w;
                }
            }
        }
#pragma unroll
        for (int n = 0; n < 5; ++n) {
            float m_new = fmaxf(m_run[n], m32[n]);
            float fo = __expf(m_run[n] - m_new);
            float fn = __expf(m32[n] - m_new);
            l_run[n] = l_run[n] * fo + l32[n] * fn;
            acc[n].x = acc[n].x * fo + fn * pv[n].x;
            acc[n].y = acc[n].y * fo + fn * pv[n].y;
            acc[n].z = acc[n].z * fo + fn * pv[n].z;
            acc[n].w = acc[n].w * fo + fn * pv[n].w;
            m_run[n] = m_new;
        }
    }
#pragma unroll
    for (int n = 0; n < 5; ++n) {
        int u = i * 5 + n;
        size_t base = ((size_t)(bhl * CH + c) * UTOP + u);
        if (j == 0) {
            part_m[base] = m_run[n];
            part_l[base] = l_run[n];
        }
        *((float4*)&part_acc[base * DD + (j << 2)]) = acc[n];
    }
}

// ---------------- Kernel E (fused scatter): combine partials, write out directly.
__global__ __launch_bounds__(64) void kE_combine(const float* __restrict__ part_m,
                                                 const float* __restrict__ part_l,
                                                 const float* __restrict__ part_acc,
                                                 const int* __restrict__ Mtop,
                                                 const int* __restrict__ Winfo,
                                                 float* __restrict__ out) {
    int bhl = blockIdx.x & 15;
    int u = blockIdx.x >> 4;
    int q = Mtop[bhl * UTOP + u];
    int r;
    if (q < UTOP - 1) r = q;
    else { if (q != Winfo[bhl]) return; r = UTOP - 1; }
    int lane = threadIdx.x;
    float mc = -INFINITY, lc = 0.f;
    if (lane < CH) {
        mc = part_m[(size_t)(bhl * CH + lane) * UTOP + u];
        lc = part_l[(size_t)(bhl * CH + lane) * UTOP + u];
    }
    float m = mc;
#pragma unroll
    for (int off = 1; off < 64; off <<= 1) m = fmaxf(m, __shfl_xor(m, off));
    float alpha = __expf(mc - m);          // 0 for inactive lanes
    float lsum = lc * alpha;
#pragma unroll
    for (int off = 1; off < 64; off <<= 1) lsum += __shfl_xor(lsum, off);
    float accd = 0.f;
    for (int c = 0; c < CH; ++c) {
        float a = __shfl(alpha, c);
        accd += a * part_acc[((size_t)(bhl * CH + c) * UTOP + u) * DD + lane];
    }
    int b = bhl >> 3, h = bhl & 7;
    out[(((size_t)(b * UTOP + r)) * NH + h) * DD + lane] = accd / lsum;
}

extern "C" void kernel_launch(void* const* d_in, const int* in_sizes, int n_in,
                              void* d_out, int out_size, void* d_ws, size_t ws_size,
                              hipStream_t stream) {
    const float* Q = (const float*)d_in[0];
    const float* K = (const float*)d_in[1];
    const float* V = (const float*)d_in[2];
    const int* idxs = (const int*)d_in[3];
    float* out = (float*)d_out;

    char* base = (char*)d_ws;
    float* M        = (float*)(base + 0);          // 131072 B
    int*   Mtop     = (int*)  (base + 131072);     // 5120 B
    int*   Winfo    = (int*)  (base + 136192);     // 64 B
    float* part_m   = (float*)(base + 136256);     // 163840 B
    float* part_l   = (float*)(base + 300096);     // 163840 B
    float* part_acc = (float*)(base + 463936);     // 10485760 B

    kA_M   <<<8192 + 16, 256, 0, stream>>>(Q, K, V, idxs, M, out);
    kB_topk<<<16,   256, 0, stream>>>(M, Mtop, Winfo);
    kD_attn<<<16 * CH, 256, 0, stream>>>(Q, K, V, Mtop, part_m, part_l, part_acc);
    kE_combine<<<16 * UTOP, 64, 0, stream>>>(part_m, part_l, part_acc, Mtop, Winfo, out);
}

// Round 12
// 132.284 us; speedup vs baseline: 1.4742x; 1.0126x over previous
//
#include <hip/hip_runtime.h>
#include <math.h>

#define LQ 2048
#define NH 8
#define DD 64
#define SK 80
#define UTOP 80
#define NB 2
#define CH 32        // number of key chunks per (b,h)
#define CK2 64       // keys per chunk (processed as 2 sub-chunks of 32)
#define CKS 32       // keys per sub-chunk

// ---------------- Kernel A (fused with V_mean fill) ----------------------------
// Wave = one (b,h,l). 8 lanes per sample: lane owns 2 float4s of the 256B K row
// (whole-row contiguous reads — line-touches/sample unchanged vs R8's 16-lane
// form), 10 sample-batches x 2 gathers all in flight. Per-sample reduce is now
// 3 VALU-pipe DPP adds (quad xor1, quad xor2, ROW_HALF_MIRROR — 8-lane groups
// are aligned half-rows) with 8 fma per iter: sample-loop VALU 200 -> 130.
// History: 16-lane DPP form = 37us (R8); 4-lane form regressed via 4x line
// requests (R7); wave-uniform form regressed via index VGPR pressure (R9).
__global__ __launch_bounds__(256) void kA_M(const float* __restrict__ Q,
                                            const float* __restrict__ K,
                                            const float* __restrict__ V,
                                            const int* __restrict__ idxs,
                                            float* __restrict__ M,
                                            float* __restrict__ out) {
    __shared__ float4 red[16][16];
    int tid = threadIdx.x;
    int x = blockIdx.x;
    if (x < 16) {
        // ---- V_mean fill: one block per (b,h) ----
        int b = x >> 3, h = x & 7;
        int d4 = tid & 15, ls = tid >> 4;
        const float4* V4 = (const float4*)V;
        float4 s = make_float4(0.f, 0.f, 0.f, 0.f);
        for (int i = 0; i < 128; ++i) {
            int l = (i << 4) + ls;
            float4 v = V4[(((size_t)(b * LQ + l) * NH + h) << 4) + d4];
            s.x += v.x; s.y += v.y; s.z += v.z; s.w += v.w;
        }
        red[ls][d4] = s;
        __syncthreads();
        if (ls == 0) {
            float4 t = red[0][d4];
            for (int k = 1; k < 16; ++k) {
                float4 r = red[k][d4];
                t.x += r.x; t.y += r.y; t.z += r.z; t.w += r.w;
            }
            t.x *= (1.f / 2048.f); t.y *= (1.f / 2048.f);
            t.z *= (1.f / 2048.f); t.w *= (1.f / 2048.f);
            red[0][d4] = t;
        }
        __syncthreads();
        float4* out4 = (float4*)out;
        for (int f = tid; f < UTOP * 16; f += 256) {
            int r = f >> 4, dd = f & 15;
            out4[(((size_t)(b * UTOP + r) * NH + h) << 4) + dd] = red[0][dd];
        }
        return;
    }
    x -= 16;                            // 16 % 8 == 0: XCD parity preserved
    int h = x & 7;                      // XCD-pinned head
    int b = (x >> 3) & 1;
    int l = ((x >> 4) << 2) + (tid >> 6);   // one l per wave
    int lane = tid & 63;
    int g = lane >> 3;                  // sample group 0..7 (aligned half-row)
    int t = lane & 7;                   // float4 slot within first half of row
    const float4* Q4 = (const float4*)Q;
    const float4* K4 = (const float4*)K;
    size_t qb = (((size_t)(b * LQ + l) * NH + h) << 4);
    float4 q4a = Q4[qb + t];
    float4 q4b = Q4[qb + 8 + t];
    const int* idxrow = idxs + l * SK;
    int kidx[10];
#pragma unroll
    for (int it = 0; it < 10; ++it) kidx[it] = idxrow[(it << 3) + g];
    __builtin_amdgcn_sched_barrier(0);   // all 10 index loads issued first
    float4 kba[10], kbb[10];
#pragma unroll
    for (int it = 0; it < 10; ++it) {
        size_t rb = (((size_t)(b * LQ + kidx[it]) * NH + h) << 4);
        kba[it] = K4[rb + t];
        kbb[it] = K4[rb + 8 + t];
    }
    __builtin_amdgcn_sched_barrier(0);   // all 20 gathers in flight before use
    float maxv = -INFINITY, sumv = 0.f;
#pragma unroll
    for (int it = 0; it < 10; ++it) {
        float4 ka = kba[it], kb = kbb[it];
        float p = q4a.x * ka.x + q4a.y * ka.y + q4a.z * ka.z + q4a.w * ka.w
                + q4b.x * kb.x + q4b.y * kb.y + q4b.z * kb.z + q4b.w * kb.w;
        // 8-lane allreduce on the VALU pipe (row-local DPP):
        p += __int_as_float(__builtin_amdgcn_update_dpp(
                 0, __float_as_int(p), 177, 0xf, 0xf, false));   // quad xor1
        p += __int_as_float(__builtin_amdgcn_update_dpp(
                 0, __float_as_int(p), 78, 0xf, 0xf, false));    // quad xor2
        p += __int_as_float(__builtin_amdgcn_update_dpp(
                 0, __float_as_int(p), 0x141, 0xf, 0xf, false)); // half mirror
        maxv = fmaxf(maxv, p);
        sumv += p;
    }
    // combine the 8 groups (each lane of a group holds identical values)
    maxv = fmaxf(maxv, __shfl_xor(maxv, 8));
    maxv = fmaxf(maxv, __shfl_xor(maxv, 16));
    maxv = fmaxf(maxv, __shfl_xor(maxv, 32));
    sumv += __shfl_xor(sumv, 8);
    sumv += __shfl_xor(sumv, 16);
    sumv += __shfl_xor(sumv, 32);
    if (lane == 0) M[(b * NH + h) * LQ + l] = maxv - sumv * (1.f / 2048.f);
}

// ---------------- Kernel B: exact top-80 SET via 48-bit radix select ------------
__global__ __launch_bounds__(256) void kB_topk(const float* __restrict__ M,
                                               int* __restrict__ Mtop,
                                               int* __restrict__ Winfo) {
    int bh = blockIdx.x;  // 0..15 == b*8+h
    int tid = threadIdx.x;
    int lane = tid & 63, w = tid >> 6;
    __shared__ unsigned long long keys[LQ];   // 16 KB
    __shared__ int hist[256];
    __shared__ int wavered[4];
    __shared__ int s_need;
    __shared__ unsigned long long s_prefix;
    __shared__ int s_cnt;
    __shared__ unsigned long long s_win;
    const float* Mrow = M + bh * LQ;
#pragma unroll
    for (int i = 0; i < 8; ++i) {
        int e = i * 256 + tid;                       // coalesced
        unsigned int bits = __float_as_uint(Mrow[e]);
        bits ^= (unsigned int)(((int)bits >> 31)) | 0x80000000u;   // monotone
        keys[e] = ((unsigned long long)bits << 16) | (unsigned int)(2047 - e);
    }
    if (tid == 0) { s_need = UTOP; s_prefix = 0ull; s_cnt = 0; s_win = ~0ull; }
    __syncthreads();
#pragma unroll
    for (int pass = 0; pass < 6; ++pass) {
        int shift = 40 - pass * 8;
        int need = s_need;
        unsigned long long pref = s_prefix;
        hist[tid] = 0;
        __syncthreads();
        unsigned long long prefmask = ~((1ull << (shift + 8)) - 1ull);
#pragma unroll
        for (int i = 0; i < 8; ++i) {
            unsigned long long k = keys[i * 256 + tid];
            if ((k & prefmask) == pref)
                atomicAdd(&hist[(int)((k >> shift) & 255)], 1);
        }
        __syncthreads();
        int b = 255 - tid;                 // suffix count via prefix scan on tid
        int v = hist[b];
        int x = v;
#pragma unroll
        for (int off = 1; off < 64; off <<= 1) {
            int y = __shfl_up(x, off);
            if (lane >= off) x += y;
        }
        if (lane == 63) wavered[w] = x;
        __syncthreads();
        int add = 0;
        for (int ww = 0; ww < w; ++ww) add += wavered[ww];
        int C = x + add;                   // = count of keys in bins >= b
        if (C >= need && C - v < need) {   // crossing bin (exactly one thread)
            s_need = need - (C - v);
            s_prefix = pref | ((unsigned long long)b << shift);
        }
        __syncthreads();
    }
    unsigned long long kth = s_prefix;     // exact 80th-largest key
#pragma unroll
    for (int i = 0; i < 8; ++i) {
        unsigned long long k = keys[i * 256 + tid];
        if (k >= kth) {
            int slot = atomicAdd(&s_cnt, 1);
            int q = 2047 - (int)(k & 0xffffu);
            Mtop[bh * UTOP + slot] = q;
            if (q >= UTOP - 1) atomicMin(&s_win, k);   // last-in-rank among idx>=79
        }
    }
    __syncthreads();
    if (tid == 0) Winfo[bh] = 2047 - (int)(s_win & 0xffffu);
}

// ---------------- Kernel D: flash partials over 64-key chunks (2x32 sub-chunks) -
__global__ __launch_bounds__(256) void kD_attn(const float* __restrict__ Q,
                                               const float* __restrict__ K,
                                               const float* __restrict__ V,
                                               const int* __restrict__ Mtop,
                                               float* __restrict__ part_m,
                                               float* __restrict__ part_l,
                                               float* __restrict__ part_acc) {
    int code = blockIdx.x & 15;
    int b = code & 1, h = code >> 1;
    int bhl = b * NH + h;
    int c = blockIdx.x >> 4;                  // 0..31
    __shared__ int topl[UTOP];
    __shared__ __align__(16) float Qs[UTOP][68];
    __shared__ __align__(16) float Ks[CKS][68];
    __shared__ __align__(16) float Vs[CKS][68];
    __shared__ __align__(16) float Ps[UTOP][36];   // 16B-aligned rows for b128
    int tid = threadIdx.x;
    if (tid < UTOP) topl[tid] = Mtop[bhl * UTOP + tid];
    __syncthreads();
    for (int f = tid; f < UTOP * 16; f += 256) {
        int u = f >> 4, t4 = f & 15;
        const float4* src = (const float4*)(Q + (((size_t)(b * LQ + topl[u]) * NH + h) << 6));
        *((float4*)&Qs[u][t4 << 2]) = src[t4];
    }
    int i = tid >> 4, j = tid & 15;
    const float scale = 0.125f;
    float4 acc[5];
    float m_run[5], l_run[5];
#pragma unroll
    for (int n = 0; n < 5; ++n) {
        acc[n] = make_float4(0.f, 0.f, 0.f, 0.f);
        m_run[n] = -INFINITY;
        l_run[n] = 0.f;
    }
    for (int sc = 0; sc < 2; ++sc) {
        __syncthreads();
        int kbase = c * CK2 + sc * CKS;
        for (int f = tid; f < CKS * 16; f += 256) {
            int k = f >> 4, t4 = f & 15;
            const float4* srck = (const float4*)(K + (((size_t)(b * LQ + kbase + k) * NH + h) << 6));
            *((float4*)&Ks[k][t4 << 2]) = srck[t4];
            const float4* srcv = (const float4*)(V + (((size_t)(b * LQ + kbase + k) * NH + h) << 6));
            *((float4*)&Vs[k][t4 << 2]) = srcv[t4];
        }
        __syncthreads();
        float s0[5], s1[5];
#pragma unroll
        for (int n = 0; n < 5; ++n) { s0[n] = 0.f; s1[n] = 0.f; }
#pragma unroll
        for (int d4 = 0; d4 < 16; ++d4) {
            float4 ka = *((float4*)&Ks[j][d4 << 2]);
            float4 kb = *((float4*)&Ks[j + 16][d4 << 2]);
#pragma unroll
            for (int n = 0; n < 5; ++n) {
                float4 q4 = *((float4*)&Qs[i * 5 + n][d4 << 2]);
                s0[n] += q4.x * ka.x + q4.y * ka.y + q4.z * ka.z + q4.w * ka.w;
                s1[n] += q4.x * kb.x + q4.y * kb.y + q4.z * kb.z + q4.w * kb.w;
            }
        }
        float m32[5], l32[5];
#pragma unroll
        for (int n = 0; n < 5; ++n) {
            float a = s0[n] * scale, bb = s1[n] * scale;
            float m = fmaxf(a, bb);
#pragma unroll
            for (int off = 1; off < 16; off <<= 1) m = fmaxf(m, __shfl_xor(m, off, 16));
            float p0 = __expf(a - m), p1 = __expf(bb - m);
            float ls = p0 + p1;
#pragma unroll
            for (int off = 1; off < 16; off <<= 1) ls += __shfl_xor(ls, off, 16);
            int u = i * 5 + n;
            Ps[u][j] = p0;
            Ps[u][j + 16] = p1;
            m32[n] = m;
            l32[n] = ls;
        }
        __syncthreads();
        // PV: k-tiles of 8, Vs rows read once, P rows via b128 broadcast
        float4 pv[5];
#pragma unroll
        for (int n = 0; n < 5; ++n) pv[n] = make_float4(0.f, 0.f, 0.f, 0.f);
#pragma unroll
        for (int kt = 0; kt < 4; ++kt) {
            float4 pA[5], pB[5];
#pragma unroll
            for (int n = 0; n < 5; ++n) {
                pA[n] = *((float4*)&Ps[i * 5 + n][kt * 8]);
                pB[n] = *((float4*)&Ps[i * 5 + n][kt * 8 + 4]);
            }
#pragma unroll
            for (int kk = 0; kk < 8; ++kk) {
                float4 v4 = *((float4*)&Vs[kt * 8 + kk][j << 2]);
#pragma unroll
                for (int n = 0; n < 5; ++n) {
                    float p = (kk < 4) ? ((float*)&pA[n])[kk] : ((float*)&pB[n])[kk - 4];
                    pv[n].x += p * v4.x; pv[n].y += p * v4.y;
                    pv[n].z += p * v4.z; pv[n].w += p * v4.w;
                }
            }
        }
#pragma unroll
        for (int n = 0; n < 5; ++n) {
            float m_new = fmaxf(m_run[n], m32[n]);
            float fo = __expf(m_run[n] - m_new);
            float fn = __expf(m32[n] - m_new);
            l_run[n] = l_run[n] * fo + l32[n] * fn;
            acc[n].x = acc[n].x * fo + fn * pv[n].x;
            acc[n].y = acc[n].y * fo + fn * pv[n].y;
            acc[n].z = acc[n].z * fo + fn * pv[n].z;
            acc[n].w = acc[n].w * fo + fn * pv[n].w;
            m_run[n] = m_new;
        }
    }
#pragma unroll
    for (int n = 0; n < 5; ++n) {
        int u = i * 5 + n;
        size_t base = ((size_t)(bhl * CH + c) * UTOP + u);
        if (j == 0) {
            part_m[base] = m_run[n];
            part_l[base] = l_run[n];
        }
        *((float4*)&part_acc[base * DD + (j << 2)]) = acc[n];
    }
}

// ---------------- Kernel E (fused scatter): combine partials, write out directly.
__global__ __launch_bounds__(64) void kE_combine(const float* __restrict__ part_m,
                                                 const float* __restrict__ part_l,
                                                 const float* __restrict__ part_acc,
                                                 const int* __restrict__ Mtop,
                                                 const int* __restrict__ Winfo,
                                                 float* __restrict__ out) {
    int bhl = blockIdx.x & 15;
    int u = blockIdx.x >> 4;
    int q = Mtop[bhl * UTOP + u];
    int r;
    if (q < UTOP - 1) r = q;
    else { if (q != Winfo[bhl]) return; r = UTOP - 1; }
    int lane = threadIdx.x;
    float mc = -INFINITY, lc = 0.f;
    if (lane < CH) {
        mc = part_m[(size_t)(bhl * CH + lane) * UTOP + u];
        lc = part_l[(size_t)(bhl * CH + lane) * UTOP + u];
    }
    float m = mc;
#pragma unroll
    for (int off = 1; off < 64; off <<= 1) m = fmaxf(m, __shfl_xor(m, off));
    float alpha = __expf(mc - m);          // 0 for inactive lanes
    float lsum = lc * alpha;
#pragma unroll
    for (int off = 1; off < 64; off <<= 1) lsum += __shfl_xor(lsum, off);
    float accd = 0.f;
    for (int c = 0; c < CH; ++c) {
        float a = __shfl(alpha, c);
        accd += a * part_acc[((size_t)(bhl * CH + c) * UTOP + u) * DD + lane];
    }
    int b = bhl >> 3, h = bhl & 7;
    out[(((size_t)(b * UTOP + r)) * NH + h) * DD + lane] = accd / lsum;
}

extern "C" void kernel_launch(void* const* d_in, const int* in_sizes, int n_in,
                              void* d_out, int out_size, void* d_ws, size_t ws_size,
                              hipStream_t stream) {
    const float* Q = (const float*)d_in[0];
    const float* K = (const float*)d_in[1];
    const float* V = (const float*)d_in[2];
    const int* idxs = (const int*)d_in[3];
    float* out = (float*)d_out;

    char* base = (char*)d_ws;
    float* M        = (float*)(base + 0);          // 131072 B
    int*   Mtop     = (int*)  (base + 131072);     // 5120 B
    int*   Winfo    = (int*)  (base + 136192);     // 64 B
    float* part_m   = (float*)(base + 136256);     // 163840 B
    float* part_l   = (float*)(base + 300096);     // 163840 B
    float* part_acc = (float*)(base + 463936);     // 10485760 B

    kA_M   <<<8192 + 16, 256, 0, stream>>>(Q, K, V, idxs, M, out);
    kB_topk<<<16,   256, 0, stream>>>(M, Mtop, Winfo);
    kD_attn<<<16 * CH, 256, 0, stream>>>(Q, K, V, Mtop, part_m, part_l, part_acc);
    kE_combine<<<16 * UTOP, 64, 0, stream>>>(part_m, part_l, part_acc, Mtop, Winfo, out);
}